// Round 2
// baseline (81.021 us; speedup 1.0000x reference)
//
#include <hip/hip_runtime.h>

#define IN_F 512
#define OUT_F 768
#define BD 256   // discrimination features (one block each)
#define ID 16    // intermediate dim
#define ND 256   // batch
#define NSUB 4
#define NTHREADS 1024

// Block b: 1024 threads = (sub 0..3, n 0..255). 16 waves/CU.
__global__ __launch_bounds__(1024) void mbd_kernel(const float* __restrict__ x,
                                                   const float* __restrict__ T,
                                                   float* __restrict__ out) {
    __shared__ float Tl[IN_F * ID];   // 32 KB
    __shared__ float Ml[ND * ID];     // 16 KB
    __shared__ float red[NTHREADS];   // 4 KB
    const int b = blockIdx.x;
    const int t = threadIdx.x;
    const int sub = t >> 8;           // 0..3
    const int n = t & 255;            // batch row

    // ---- stage T[:, b, :] (512x16 fp32 = 32 KB) into LDS ----
    {
        const float* Tb = T + (size_t)b * ID;
        for (int k = t; k < (IN_F * ID) / 4; k += NTHREADS) {
            int f = k >> 2;            // 0..511
            int e = (k & 3) << 2;      // 0,4,8,12
            float4 v = *reinterpret_cast<const float4*>(Tb + (size_t)f * (BD * ID) + e);
            *reinterpret_cast<float4*>(&Tl[f * ID + e]) = v;
        }
    }
    __syncthreads();

    // ---- phase 1: thread (sub,n) computes m[i], i in [sub*4, sub*4+4) ----
    float m4[4] = {0.f, 0.f, 0.f, 0.f};
    {
        const float4* xr = reinterpret_cast<const float4*>(x + (size_t)n * IN_F);
        const int ibase = sub * 4;
        for (int f4 = 0; f4 < IN_F / 4; ++f4) {
            float4 xv = xr[f4];
            const float* tp = &Tl[(f4 * 4) * ID + ibase];  // wave-uniform -> broadcast
#pragma unroll
            for (int k = 0; k < 4; ++k) m4[k] = fmaf(xv.x, tp[k], m4[k]);
#pragma unroll
            for (int k = 0; k < 4; ++k) m4[k] = fmaf(xv.y, tp[ID + k], m4[k]);
#pragma unroll
            for (int k = 0; k < 4; ++k) m4[k] = fmaf(xv.z, tp[2 * ID + k], m4[k]);
#pragma unroll
            for (int k = 0; k < 4; ++k) m4[k] = fmaf(xv.w, tp[3 * ID + k], m4[k]);
        }
        *reinterpret_cast<float4*>(&Ml[n * ID + sub * 4]) =
            make_float4(m4[0], m4[1], m4[2], m4[3]);
    }
    __syncthreads();

    // ---- phase 2: sub handles j in [sub*64, sub*64+64) with full m row ----
    float mr[ID];
#pragma unroll
    for (int i = 0; i < ID; i += 4) {
        float4 v = *reinterpret_cast<const float4*>(&Ml[n * ID + i]);
        mr[i] = v.x; mr[i + 1] = v.y; mr[i + 2] = v.z; mr[i + 3] = v.w;
    }
    float acc = 0.f;
    const int j0 = sub * (ND / NSUB);
    for (int j = j0; j < j0 + ND / NSUB; ++j) {
        const float* mj = &Ml[j * ID];  // wave-uniform -> broadcast
        float s0 = 0.f, s1 = 0.f, s2 = 0.f, s3 = 0.f;
#pragma unroll
        for (int i = 0; i < ID; i += 4) {
            s0 += fabsf(mr[i + 0] - mj[i + 0]);
            s1 += fabsf(mr[i + 1] - mj[i + 1]);
            s2 += fabsf(mr[i + 2] - mj[i + 2]);
            s3 += fabsf(mr[i + 3] - mj[i + 3]);
        }
        acc += __expf(-((s0 + s1) + (s2 + s3)));
    }
    red[t] = acc;
    __syncthreads();

    if (sub == 0) {
        float r = red[n] + red[n + 256] + red[n + 512] + red[n + 768] - 1.f;
        out[(size_t)n * OUT_F + IN_F + b] = r;
    }

    // ---- concat: block b copies x row b -> out[b, 0:512] ----
    if (t < IN_F / 4) {
        const float4* xs = reinterpret_cast<const float4*>(x + (size_t)b * IN_F);
        reinterpret_cast<float4*>(out + (size_t)b * OUT_F)[t] = xs[t];
    }
}

extern "C" void kernel_launch(void* const* d_in, const int* in_sizes, int n_in,
                              void* d_out, int out_size, void* d_ws, size_t ws_size,
                              hipStream_t stream) {
    const float* x = (const float*)d_in[0];
    const float* T = (const float*)d_in[1];
    float* out = (float*)d_out;
    mbd_kernel<<<dim3(BD), dim3(NTHREADS), 0, stream>>>(x, T, out);
}

// Round 3
// 74.049 us; speedup vs baseline: 1.0941x; 1.0941x over previous
//
#include <hip/hip_runtime.h>

#define IN_F 512
#define OUT_F 768
#define BD 256   // discrimination features
#define ID 16    // intermediate dim
#define ND 256   // batch

// ---------------- K1: M[b][n][i] = sum_f x[n,f] * T[f,b,i] ----------------
// grid=256 (b), block=256 (n). T accesses are wave-uniform -> s_load (SGPR),
// x accesses per-lane float4 (VGPR). No LDS, no barriers.
__global__ __launch_bounds__(256) void proj_kernel(const float* __restrict__ x,
                                                   const float* __restrict__ T,
                                                   float* __restrict__ M) {
    const int b = blockIdx.x;
    const int n = threadIdx.x;

    float m[ID];
#pragma unroll
    for (int i = 0; i < ID; ++i) m[i] = 0.f;

    const float4* xr = reinterpret_cast<const float4*>(x + (size_t)n * IN_F);
    const float* Tb = T + (size_t)b * ID;  // T[f,b,i] = Tb[f*(BD*ID) + i]

    for (int f4 = 0; f4 < IN_F / 4; ++f4) {
        float4 xv = xr[f4];
        const float* t0 = Tb + (size_t)(4 * f4) * (BD * ID);
#pragma unroll
        for (int i = 0; i < ID; ++i) m[i] = fmaf(xv.x, t0[i], m[i]);
#pragma unroll
        for (int i = 0; i < ID; ++i) m[i] = fmaf(xv.y, t0[BD * ID + i], m[i]);
#pragma unroll
        for (int i = 0; i < ID; ++i) m[i] = fmaf(xv.z, t0[2 * BD * ID + i], m[i]);
#pragma unroll
        for (int i = 0; i < ID; ++i) m[i] = fmaf(xv.w, t0[3 * BD * ID + i], m[i]);
    }

    float4* Mo = reinterpret_cast<float4*>(M + ((size_t)b * ND + n) * ID);
#pragma unroll
    for (int i = 0; i < ID / 4; ++i)
        Mo[i] = make_float4(m[4 * i], m[4 * i + 1], m[4 * i + 2], m[4 * i + 3]);
}

// ---------------- K2: out[n,512+b] = sum_j exp(-L1(m_n, m_j)) - 1 ----------
// grid=256 (b), block=256 (n). Own row in VGPRs; mj wave-uniform -> s_load.
// No LDS, no barriers.
__global__ __launch_bounds__(256) void pair_kernel(const float* __restrict__ x,
                                                   const float* __restrict__ M,
                                                   float* __restrict__ out) {
    const int b = blockIdx.x;
    const int n = threadIdx.x;
    const float* Mb = M + (size_t)b * ND * ID;

    float m[ID];
#pragma unroll
    for (int i = 0; i < ID; i += 4) {
        float4 v = *reinterpret_cast<const float4*>(Mb + (size_t)n * ID + i);
        m[i] = v.x; m[i + 1] = v.y; m[i + 2] = v.z; m[i + 3] = v.w;
    }

    float total = 0.f;
    for (int j = 0; j < ND; ++j) {
        const float* mj = Mb + (size_t)j * ID;  // uniform -> SGPR
        float s0 = 0.f, s1 = 0.f, s2 = 0.f, s3 = 0.f;
#pragma unroll
        for (int i = 0; i < ID; i += 4) {
            s0 += fabsf(m[i + 0] - mj[i + 0]);
            s1 += fabsf(m[i + 1] - mj[i + 1]);
            s2 += fabsf(m[i + 2] - mj[i + 2]);
            s3 += fabsf(m[i + 3] - mj[i + 3]);
        }
        total += __expf(-((s0 + s1) + (s2 + s3)));
    }
    out[(size_t)n * OUT_F + IN_F + b] = total - 1.f;

    // concat: block b copies x row b -> out[b, 0:512]
    if (n < IN_F / 4) {
        const float4* xs = reinterpret_cast<const float4*>(x + (size_t)b * IN_F);
        reinterpret_cast<float4*>(out + (size_t)b * OUT_F)[n] = xs[n];
    }
}

// ---------------- Fallback (ws too small): fused, s_load T, LDS for M ------
__global__ __launch_bounds__(256) void fused_kernel(const float* __restrict__ x,
                                                    const float* __restrict__ T,
                                                    float* __restrict__ out) {
    __shared__ float Ml[ND * ID];  // 16 KB
    const int b = blockIdx.x;
    const int n = threadIdx.x;

    float m[ID];
#pragma unroll
    for (int i = 0; i < ID; ++i) m[i] = 0.f;

    const float4* xr = reinterpret_cast<const float4*>(x + (size_t)n * IN_F);
    const float* Tb = T + (size_t)b * ID;
    for (int f4 = 0; f4 < IN_F / 4; ++f4) {
        float4 xv = xr[f4];
        const float* t0 = Tb + (size_t)(4 * f4) * (BD * ID);
#pragma unroll
        for (int i = 0; i < ID; ++i) m[i] = fmaf(xv.x, t0[i], m[i]);
#pragma unroll
        for (int i = 0; i < ID; ++i) m[i] = fmaf(xv.y, t0[BD * ID + i], m[i]);
#pragma unroll
        for (int i = 0; i < ID; ++i) m[i] = fmaf(xv.z, t0[2 * BD * ID + i], m[i]);
#pragma unroll
        for (int i = 0; i < ID; ++i) m[i] = fmaf(xv.w, t0[3 * BD * ID + i], m[i]);
    }
#pragma unroll
    for (int i = 0; i < ID; i += 4)
        *reinterpret_cast<float4*>(&Ml[n * ID + i]) =
            make_float4(m[i], m[i + 1], m[i + 2], m[i + 3]);
    __syncthreads();

    float total = 0.f;
    for (int j = 0; j < ND; ++j) {
        const float* mj = &Ml[j * ID];
        float s0 = 0.f, s1 = 0.f, s2 = 0.f, s3 = 0.f;
#pragma unroll
        for (int i = 0; i < ID; i += 4) {
            s0 += fabsf(m[i + 0] - mj[i + 0]);
            s1 += fabsf(m[i + 1] - mj[i + 1]);
            s2 += fabsf(m[i + 2] - mj[i + 2]);
            s3 += fabsf(m[i + 3] - mj[i + 3]);
        }
        total += __expf(-((s0 + s1) + (s2 + s3)));
    }
    out[(size_t)n * OUT_F + IN_F + b] = total - 1.f;

    if (n < IN_F / 4) {
        const float4* xs = reinterpret_cast<const float4*>(x + (size_t)b * IN_F);
        reinterpret_cast<float4*>(out + (size_t)b * OUT_F)[n] = xs[n];
    }
}

extern "C" void kernel_launch(void* const* d_in, const int* in_sizes, int n_in,
                              void* d_out, int out_size, void* d_ws, size_t ws_size,
                              hipStream_t stream) {
    const float* x = (const float*)d_in[0];
    const float* T = (const float*)d_in[1];
    float* out = (float*)d_out;
    const size_t needed = (size_t)BD * ND * ID * sizeof(float);  // 4 MB

    if (ws_size >= needed) {
        float* M = (float*)d_ws;
        proj_kernel<<<dim3(BD), dim3(256), 0, stream>>>(x, T, M);
        pair_kernel<<<dim3(BD), dim3(256), 0, stream>>>(x, M, out);
    } else {
        fused_kernel<<<dim3(BD), dim3(256), 0, stream>>>(x, T, out);
    }
}